// Round 2
// baseline (49.876 us; speedup 1.0000x reference)
//
#include <hip/hip_runtime.h>

// TemporalCoding: out[b][t][f] = (spike_time(x[b][f]) == t && x[b][f] > 0) ? 1 : 0
// B=32, T=32, F=32768. Output 128 MiB f32 -> pure write-BW bound.
//
// R1: fill-mimicking linear write stream. One thread owns 64 B (4x float4) of
// CONSECUTIVE output within a single t-plane; global thread order == output
// address order, so the write stream is identical in shape to
// __amd_rocclr_fillBufferAligned (which measures 6.6 TB/s on this chip).
// x is re-read once per t-plane (32x logical amplification) but is 4 MiB ->
// L2/L3 resident, so HBM sees only the compulsory ~4 MiB of reads.

constexpr int T   = 32;
constexpr int B   = 32;
constexpr int F   = 32768;
constexpr int NF4 = F / 4;       // 8192 float4 per (b,t) row
constexpr int ILP = 4;           // float4s per thread (64 B)

__global__ __launch_bounds__(256)
void temporal_coding_kernel(const float4* __restrict__ x4, float4* __restrict__ out4) {
    const int gid   = blockIdx.x * blockDim.x + threadIdx.x;
    const int base4 = gid * ILP;                 // index in float4 units of output

    // all powers of two -> shifts
    const int b   = base4 >> 18;                 // / (T*NF4) = 262144
    const int t   = (base4 >> 13) & (T - 1);     // / NF4 % T
    const int f4b = base4 & (NF4 - 1);           // % NF4

    const float4* xrow = x4 + ((size_t)b << 13); // b*NF4

    float4 o[ILP];
#pragma unroll
    for (int i = 0; i < ILP; ++i) {
        const float4 xv = xrow[f4b + i];
        float v[4] = {xv.x, xv.y, xv.z, xv.w};
        float r[4];
#pragma unroll
        for (int j = 0; j < 4; ++j) {
            float xn = v[j];
            xn = xn < 0.0f ? 0.0f : xn;
            xn = xn > 1.0f ? 1.0f : xn;
            int s = (int)((1.0f - xn) * 31.0f);  // trunc == astype(int32) for s>=0
            s = s < 0 ? 0 : (s > 31 ? 31 : s);
            r[j] = (xn > 0.0f && s == t) ? 1.0f : 0.0f;
        }
        o[i].x = r[0]; o[i].y = r[1]; o[i].z = r[2]; o[i].w = r[3];
    }

#pragma unroll
    for (int i = 0; i < ILP; ++i)
        out4[(size_t)base4 + i] = o[i];
}

extern "C" void kernel_launch(void* const* d_in, const int* in_sizes, int n_in,
                              void* d_out, int out_size, void* d_ws, size_t ws_size,
                              hipStream_t stream) {
    const float4* x4 = (const float4*)d_in[0];
    float4* out4 = (float4*)d_out;

    const int total_f4   = B * T * NF4;            // 8,388,608 float4s
    const int threads    = total_f4 / ILP;         // 2,097,152
    const int block      = 256;
    const int grid       = threads / block;        // 8192
    temporal_coding_kernel<<<grid, block, 0, stream>>>(x4, out4);
}

// Round 3
// 24.829 us; speedup vs baseline: 2.0088x; 2.0088x over previous
//
#include <hip/hip_runtime.h>

// TemporalCoding: out[b][t][f] = (spike_time(x[b][f]) == t && x[b][f] > 0) ? 1 : 0
// B=32, T=32, F=32768. Output 128 MiB f32 -> pure write-BW bound.
//
// R2: fill-clone write stream with WAVE-chunked ILP (fixes R1's coalescing bug).
// Each block owns 1024 consecutive float4s (16 KiB) of output, entirely within
// one t-plane (plane = 8192 float4s, blocks aligned). Thread's k-th element is
// at lane + k*64, so every store instruction is 64 lanes x 16 B = 1 KiB
// contiguous; the global write stream is perfectly linear (same shape as
// fillBufferAligned, 6.6-6.9 TB/s measured).
// x (4 MiB) is logically re-read once per t-plane, but the 32 blocks sharing an
// x-chunk have blockIdx differing by multiples of 8 -> same XCD under
// round-robin -> served from that XCD's L2 after first touch.

constexpr int T   = 32;
constexpr int B   = 32;
constexpr int F   = 32768;
constexpr int NF4 = F / 4;       // 8192 float4 per (b,t) plane

__global__ __launch_bounds__(256)
void temporal_coding_kernel(const float4* __restrict__ x4, float4* __restrict__ out4) {
    const unsigned bid = blockIdx.x;          // enumerates (b, t, chunk): b*256 + t*8 + c
    const unsigned tid = threadIdx.x;

    const int      t    = (bid >> 3) & (T - 1);
    const float4*  xrow = x4 + ((size_t)(bid >> 8) << 13);        // + b*NF4
    const unsigned sub  = ((tid >> 6) << 8) | (tid & 63);         // wave*256 + lane
    const unsigned f4_0 = ((bid & 7) << 10) + sub;                // f4 index, k=0
    float4*        op   = out4 + (((size_t)bid) << 10) + sub;     // linear: bid*1024

#pragma unroll
    for (int k = 0; k < 4; ++k) {
        const float4 xv = xrow[f4_0 + k * 64];
        float v[4] = {xv.x, xv.y, xv.z, xv.w};
        float r[4];
#pragma unroll
        for (int j = 0; j < 4; ++j) {
            float xn = v[j];
            xn = xn < 0.0f ? 0.0f : (xn > 1.0f ? 1.0f : xn);
            int s = (int)((1.0f - xn) * 31.0f);   // trunc == astype(int32) for s>=0
            s = s < 0 ? 0 : (s > 31 ? 31 : s);
            r[j] = (xn > 0.0f && s == t) ? 1.0f : 0.0f;
        }
        op[k * 64] = make_float4(r[0], r[1], r[2], r[3]);
    }
}

extern "C" void kernel_launch(void* const* d_in, const int* in_sizes, int n_in,
                              void* d_out, int out_size, void* d_ws, size_t ws_size,
                              hipStream_t stream) {
    const float4* x4 = (const float4*)d_in[0];
    float4* out4 = (float4*)d_out;

    const int grid = B * T * (NF4 / 1024);   // 8192 blocks x 256 threads, 4 float4/thread
    temporal_coding_kernel<<<grid, 256, 0, stream>>>(x4, out4);
}